// Round 7
// baseline (159.460 us; speedup 1.0000x reference)
//
#include <hip/hip_runtime.h>
#include <stdint.h>

#define M_NODES 4001
#define NW 63            // ceil(4001/64) bitmask words per row
#define DIM 128
#define THRESH 0.04f
#define CAP 64           // neighbor cap (validated r1/r5/r6)
#define SENTINEL 4095    // bit 4095 never set in m2row (word 63 == 0)
#define MAXJ 512         // cap on |M2(i)| (mean ~80, max ~200)
#define ADJ_RG 16        // row-groups of 256 rows
#define ADJ_BLOCKS (ADJ_RG * NW)   // 1008

// ROUND-7 NOTE: r1/r6 nulls exclude BW + block count; by elimination fv2
// (~25us of K~40) is latency-bound on its per-j ballot convoy:
// global u -> dependent LDS m2row read -> wave-wide __ballot per j.
// This round replaces it with a transposed popc-AND count phase
// (count_j = sum_w popc(m2row[w] & A[j][w]), lane<->j, wave<->word-range,
// streaming loads, no cross-lane sync) + a separate weighted-sum phase whose
// accumulation order is bitwise-identical to r6 (absmax must stay 0.25).

typedef unsigned short u16;

// 6-step inclusive shfl scan over 64 lanes.
__device__ __forceinline__ int wave64_incl_scan(int v, int lane) {
#pragma unroll
    for (int d = 1; d < 64; d <<= 1) {
        int n = __shfl_up(v, d, 64);
        if (lane >= d) v += n;
    }
    return v;
}

// ---------- kernel 1: adjacency bitmask tiles (r0 shape, unchanged) ----------
__global__ void prep_kernel(const float* __restrict__ node_loc,
                            const float* __restrict__ depot,
                            uint64_t* __restrict__ A) {
    __shared__ float2 cand[64];
    int tid = threadIdx.x;
    int rg = blockIdx.x & (ADJ_RG - 1);
    int w  = blockIdx.x >> 4;          // 0..62
    if (tid < 64) {
        int j = w * 64 + tid;
        float2 c;
        if (j == 0) { c.x = depot[0]; c.y = depot[1]; }
        else if (j < M_NODES) { c.x = node_loc[(j - 1) * 2]; c.y = node_loc[(j - 1) * 2 + 1]; }
        else { c.x = 1e9f; c.y = 1e9f; }
        cand[tid] = c;
    }
    int i = rg * 256 + tid;
    float xi = 0.f, yi = 0.f;
    if (i == 0) { xi = depot[0]; yi = depot[1]; }
    else if (i < M_NODES) { xi = node_loc[(i - 1) * 2]; yi = node_loc[(i - 1) * 2 + 1]; }
    __syncthreads();
    uint64_t m = 0;
#pragma unroll
    for (int b = 0; b < 64; ++b) {
#pragma clang fp contract(off)
        float dx = xi - cand[b].x;
        float dy = yi - cand[b].y;
        float xx = dx * dx;
        float yy = dy * dy;
        float d2 = xx + yy;
        if (sqrtf(d2) <= THRESH) m |= (1ull << b);
    }
    if (i < M_NODES) A[(size_t)i * NW + w] = m;
}

// ---------- kernel 2: CSR build + fv1, fv0 in registers (r6 unchanged) ----------
__global__ void fv1csr_kernel(const uint64_t* __restrict__ A,
                              const float* __restrict__ node_loc,
                              const float* __restrict__ td,
                              const float* __restrict__ depot,
                              const float* __restrict__ W0w,
                              const float* __restrict__ W0b,
                              u16* __restrict__ nbr16, int* __restrict__ deg,
                              float* __restrict__ fv1) {
    __shared__ u16 slist[CAP];
    __shared__ float2 part[4][64];
    __shared__ int snn;
    int i = blockIdx.x, tid = threadIdx.x, lane = tid & 63, wave = tid >> 6;

    if (tid < 64) {
        uint64_t m = (tid < NW) ? A[(size_t)i * NW + tid] : 0ull;
        int c = __popcll(m);
        int incl = wave64_incl_scan(c, tid);
        int oo = incl - c;
        int base = tid * 64;
        while (m) {
            int b = __builtin_ctzll(m);
            if (oo < CAP) { slist[oo] = (u16)(base + b); nbr16[(size_t)i * CAP + oo] = (u16)(base + b); }
            ++oo;
            m &= m - 1;
        }
        int tot = __shfl(incl, 63, 64);
        if (tot > CAP) tot = CAP;
        if (tid == 0) { deg[i] = tot; snn = tot; }
        int s = tot + tid;                       // sentinel-pad slots [tot,CAP)
        if (s < CAP) nbr16[(size_t)i * CAP + s] = (u16)SENTINEL;
    }
    __syncthreads();

    int n1 = snn;
    int d0 = 2 * lane;
    float w00 = W0w[d0 * 3],     w01 = W0w[d0 * 3 + 1], w02 = W0w[d0 * 3 + 2];
    float w10 = W0w[d0 * 3 + 3], w11 = W0w[d0 * 3 + 4], w12 = W0w[d0 * 3 + 5];
    float b0 = W0b[d0], b1 = W0b[d0 + 1];
    float2 acc = {0.f, 0.f};
    for (int l = wave; l < n1; l += 4) {
        int j = slist[l];
        float xj, yj, tj;
        if (j == 0) { xj = depot[0]; yj = depot[1]; tj = 0.f; }
        else { xj = node_loc[(j - 1) * 2]; yj = node_loc[(j - 1) * 2 + 1]; tj = td[j - 1]; }
        float v0 = fmaf(xj, w00, fmaf(yj, w01, fmaf(tj, w02, b0)));
        float v1 = fmaf(xj, w10, fmaf(yj, w11, fmaf(tj, w12, b1)));
        acc.x += v0 > 0.f ? v0 : 0.f;
        acc.y += v1 > 0.f ? v1 : 0.f;
    }
    part[wave][lane] = acc;
    __syncthreads();
    if (wave == 0) {
        float2 p1 = part[1][lane], p2 = part[2][lane], p3 = part[3][lane];
        float2 s = { ((acc.x + p1.x) + p2.x) + p3.x,
                     ((acc.y + p1.y) + p2.y) + p3.y };
        ((float2*)fv1)[(size_t)i * 64 + lane] = s;
    }
}

// ---------- kernel 3: fv_2 with transposed popc-AND counts ----------
// count_j = |M2(i) ∩ N(j)| = sum_w popcll(m2row[w] & A[j][w]) — exact, and
// identical to the old ballot count (sentinel entries hit word 63 == 0).
__global__ void fv2_kernel(const uint64_t* __restrict__ A,
                           const u16* __restrict__ nbr16, const int* __restrict__ deg,
                           const float* __restrict__ fv1, float* __restrict__ out) {
    __shared__ uint64_t m2part[4][64];
    __shared__ uint64_t m2row[64];
    __shared__ int list1[CAP];
    __shared__ u16 list2[MAXJ];
    __shared__ float counts[MAXJ];
    __shared__ int cntpart[4][64];
    __shared__ float2 wacc[3][64];
    __shared__ int snn2;

    int i = blockIdx.x, tid = threadIdx.x;
    int lane = tid & 63, wave = tid >> 6;
    int n1 = deg[i];
    if (tid < CAP) list1[tid] = (tid < n1) ? (int)nbr16[(size_t)i * CAP + tid] : 0;
    __syncthreads();

    // M2 row i = OR over j in N(i) of A row j (coalesced 504B rows), unroll-2.
    uint64_t o = 0;
    {
        int l = wave;
        for (; l + 4 < n1; l += 8) {
            uint64_t a0 = (lane < NW) ? A[(size_t)list1[l] * NW + lane] : 0ull;
            uint64_t a1 = (lane < NW) ? A[(size_t)list1[l + 4] * NW + lane] : 0ull;
            o |= a0 | a1;
        }
        if (l < n1) o |= (lane < NW) ? A[(size_t)list1[l] * NW + lane] : 0ull;
    }
    m2part[wave][lane] = o;
    __syncthreads();

    // wave 0: combine, scan, deterministic ascending enumerate of M2(i).
    if (tid < 64) {
        uint64_t m = m2part[0][tid] | m2part[1][tid] | m2part[2][tid] | m2part[3][tid];
        m2row[tid] = m;
        int c = __popcll(m);
        int incl = wave64_incl_scan(c, tid);
        int oo = incl - c;
        int base = tid * 64;
        while (m) {
            int b = __builtin_ctzll(m);
            if (oo < MAXJ) list2[oo] = (u16)(base + b);
            ++oo;
            m &= m - 1;
        }
        if (tid == 63) snn2 = incl < MAXJ ? incl : MAXJ;
    }
    __syncthreads();
    int n2 = snn2;

    // count phase (transposed): lane <-> j (64 j's/batch), wave <-> word range
    // (16 words each). Streaming per-lane row loads with immediate offsets; no
    // cross-lane sync in the load path. Padding lanes read row 0, gated at write.
    int w0 = wave * 16;
    int nb = (n2 + 63) >> 6;
    for (int b = 0; b < nb; ++b) {
        int myj = b * 64 + lane;
        int jj = (myj < n2) ? (int)list2[myj] : 0;
        const uint64_t* ar = A + (size_t)jj * NW + w0;
        int cnt = 0;
#pragma unroll
        for (int k = 0; k < 16; ++k) {
            if (w0 + k < NW) cnt += __popcll(ar[k] & m2row[w0 + k]);
        }
        cntpart[wave][lane] = cnt;
        __syncthreads();
        if (tid < 64) {
            int jw = b * 64 + tid;
            if (jw < n2)
                counts[jw] = (float)(cntpart[0][tid] + cntpart[1][tid]
                                   + cntpart[2][tid] + cntpart[3][tid]);
        }
        __syncthreads();
    }

    // weighted sum: wave per j stride 4, unroll-4, ascending accumulation —
    // bitwise-identical order to r6 (counts are the same exact small ints).
    const float2* fv1v = (const float2*)fv1;     // row = 64 float2
    float2 acc = {0.f, 0.f};
    int l = wave;
    for (; l + 12 < n2; l += 16) {
        int j0 = list2[l];
        int j1 = list2[l + 4];
        int j2 = list2[l + 8];
        int j3 = list2[l + 12];
        float2 r0 = fv1v[(size_t)j0 * 64 + lane];    // 512B coalesced
        float2 r1 = fv1v[(size_t)j1 * 64 + lane];
        float2 r2 = fv1v[(size_t)j2 * 64 + lane];
        float2 r3 = fv1v[(size_t)j3 * 64 + lane];
        float c0 = counts[l];
        float c1 = counts[l + 4];
        float c2 = counts[l + 8];
        float c3 = counts[l + 12];
        acc.x = fmaf(c0, r0.x, acc.x); acc.y = fmaf(c0, r0.y, acc.y);
        acc.x = fmaf(c1, r1.x, acc.x); acc.y = fmaf(c1, r1.y, acc.y);
        acc.x = fmaf(c2, r2.x, acc.x); acc.y = fmaf(c2, r2.y, acc.y);
        acc.x = fmaf(c3, r3.x, acc.x); acc.y = fmaf(c3, r3.y, acc.y);
    }
    for (; l < n2; l += 4) {
        int j0 = list2[l];
        float2 r0 = fv1v[(size_t)j0 * 64 + lane];
        float c0 = counts[l];
        acc.x = fmaf(c0, r0.x, acc.x); acc.y = fmaf(c0, r0.y, acc.y);
    }
    if (wave > 0) wacc[wave - 1][lane] = acc;
    __syncthreads();
    if (wave == 0) {
        float2 s0 = wacc[0][lane], s1 = wacc[1][lane], s2 = wacc[2][lane];
        float2 s = { acc.x + s0.x + s1.x + s2.x, acc.y + s0.y + s1.y + s2.y };
        ((float2*)out)[(size_t)i * 64 + lane] = s;   // coalesced 512B
    }
}

extern "C" void kernel_launch(void* const* d_in, const int* in_sizes, int n_in,
                              void* d_out, int out_size, void* d_ws, size_t ws_size,
                              hipStream_t stream) {
    const float* node_loc = (const float*)d_in[0];  // [4000,2]
    const float* td       = (const float*)d_in[1];  // [4000,1]
    const float* depot    = (const float*)d_in[2];  // [1,2]
    const float* W0w      = (const float*)d_in[3];  // [128,3]
    const float* W0b      = (const float*)d_in[4];  // [128]
    float* out = (float*)d_out;                     // [4001,128]

    char* base = (char*)d_ws;
    size_t off = 0;
    auto carve = [&](size_t bytes) {
        char* p = base + off;
        off = (off + bytes + 511) & ~(size_t)511;
        return p;
    };
    uint64_t* A     = (uint64_t*)carve((size_t)M_NODES * NW * sizeof(uint64_t));  // ~2.0 MB
    float*    fv1   = (float*)   carve((size_t)M_NODES * DIM * sizeof(float));    // ~2.0 MB
    u16*      nbr16 = (u16*)     carve((size_t)M_NODES * CAP * sizeof(u16));      // ~0.5 MB
    int*      deg   = (int*)     carve((size_t)M_NODES * sizeof(int));            // 16 KB

    prep_kernel<<<ADJ_BLOCKS, 256, 0, stream>>>(node_loc, depot, A);
    fv1csr_kernel<<<M_NODES, 256, 0, stream>>>(A, node_loc, td, depot, W0w, W0b,
                                               nbr16, deg, fv1);
    fv2_kernel<<<M_NODES, 256, 0, stream>>>(A, nbr16, deg, fv1, out);
}

// Round 8
// 109.239 us; speedup vs baseline: 1.4597x; 1.4597x over previous
//
#include <hip/hip_runtime.h>
#include <stdint.h>

#define M_NODES 4001
#define NW 63            // ceil(4001/64) bitmask words per row
#define THRESH 0.04f
#define CAP 64           // neighbor cap (validated r1/r5/r6; P(Poisson(20.1)>64) ~ 1e-15)
#define SENTINEL 4095    // bit 4095 never set in m2row (word 63 == 0)
#define MAXJ 512         // cap on |M2(i)| (mean ~80, max ~200)
#define ADJ_RG 16        // row-groups of 256 rows
#define ADJ_BLOCKS (ADJ_RG * NW)        // 1008
#define NODE_BLOCKS ((M_NODES + 3) / 4) // 1001 (4 waves/block, wave-per-node)

// ROUND-8 NOTE: r7 gave direct evidence: fv2(transposed)=82us, VALUBusy 10%,
// HBM 3% -> latency-bound, and algebra pins fv1csr ~14us, fv2(ballot) ~24us,
// fixed harness ~61us. Both big kernels were barrier-phase latency chains with
// wave-0-only sections. This round: WAVE-PER-NODE, ZERO barriers, whole grid
// co-resident (1001 blocks x 4 independent waves). fv1csr needs no LDS at all;
// fv2 keeps the validated ballot count with per-wave LDS slices.

typedef unsigned short u16;

// 6-step inclusive shfl scan over 64 lanes.
__device__ __forceinline__ int wave64_incl_scan(int v, int lane) {
#pragma unroll
    for (int d = 1; d < 64; d <<= 1) {
        int n = __shfl_up(v, d, 64);
        if (lane >= d) v += n;
    }
    return v;
}

// ---------- kernel 1: adjacency bitmask tiles (r0 shape, unchanged) ----------
// Predicate bit-matches numpy: contract(off) d2, correctly-rounded sqrtf, <= 0.04f.
__global__ void prep_kernel(const float* __restrict__ node_loc,
                            const float* __restrict__ depot,
                            uint64_t* __restrict__ A) {
    __shared__ float2 cand[64];
    int tid = threadIdx.x;
    int rg = blockIdx.x & (ADJ_RG - 1);
    int w  = blockIdx.x >> 4;          // 0..62
    if (tid < 64) {
        int j = w * 64 + tid;
        float2 c;
        if (j == 0) { c.x = depot[0]; c.y = depot[1]; }
        else if (j < M_NODES) { c.x = node_loc[(j - 1) * 2]; c.y = node_loc[(j - 1) * 2 + 1]; }
        else { c.x = 1e9f; c.y = 1e9f; }
        cand[tid] = c;
    }
    int i = rg * 256 + tid;
    float xi = 0.f, yi = 0.f;
    if (i == 0) { xi = depot[0]; yi = depot[1]; }
    else if (i < M_NODES) { xi = node_loc[(i - 1) * 2]; yi = node_loc[(i - 1) * 2 + 1]; }
    __syncthreads();
    uint64_t m = 0;
#pragma unroll
    for (int b = 0; b < 64; ++b) {
#pragma clang fp contract(off)
        float dx = xi - cand[b].x;
        float dy = yi - cand[b].y;
        float xx = dx * dx;
        float yy = dy * dy;
        float d2 = xx + yy;
        if (sqrtf(d2) <= THRESH) m |= (1ull << b);
    }
    if (i < M_NODES) A[(size_t)i * NW + w] = m;
}

// ---------- kernel 2: wave-per-node CSR + fv1, no LDS, no barriers ----------
// Wave = node i. A row in registers; neighbors enumerated in ascending order by
// uniform word-broadcast; CSR entry captured into a per-lane register (tot==lane);
// fv0 recomputed inline (3 broadcast loads + 6 FMA per neighbor, validated r5/r6).
__global__ void fv1csr_kernel(const uint64_t* __restrict__ A,
                              const float* __restrict__ node_loc,
                              const float* __restrict__ td,
                              const float* __restrict__ depot,
                              const float* __restrict__ W0w,
                              const float* __restrict__ W0b,
                              u16* __restrict__ nbr16, int* __restrict__ deg,
                              float* __restrict__ fv1) {
    int tid = threadIdx.x, lane = tid & 63, wave = tid >> 6;
    int i = blockIdx.x * 4 + wave;
    if (i >= M_NODES) return;

    uint64_t a = (lane < NW) ? A[(size_t)i * NW + lane] : 0ull;

    int d0 = 2 * lane;                 // lane owns output dims (d0, d0+1)
    float w00 = W0w[d0 * 3],     w01 = W0w[d0 * 3 + 1], w02 = W0w[d0 * 3 + 2];
    float w10 = W0w[d0 * 3 + 3], w11 = W0w[d0 * 3 + 4], w12 = W0w[d0 * 3 + 5];
    float b0 = W0b[d0], b1 = W0b[d0 + 1];

    u16 myent = (u16)SENTINEL;
    int tot = 0;
    float2 acc = {0.f, 0.f};
    for (int w = 0; w < NW; ++w) {
        uint64_t mw = (uint64_t)__shfl((long long)a, w, 64);   // uniform word
        while (mw) {
            int b = __builtin_ctzll(mw);
            int j = w * 64 + b;                                // uniform, ascending
            if (tot == lane) myent = (u16)j;                   // capture CSR slot
            float xj, yj, tj;
            if (j == 0) { xj = depot[0]; yj = depot[1]; tj = 0.f; }
            else { xj = node_loc[(j - 1) * 2]; yj = node_loc[(j - 1) * 2 + 1]; tj = td[j - 1]; }
            float v0 = fmaf(xj, w00, fmaf(yj, w01, fmaf(tj, w02, b0)));
            float v1 = fmaf(xj, w10, fmaf(yj, w11, fmaf(tj, w12, b1)));
            acc.x += v0 > 0.f ? v0 : 0.f;
            acc.y += v1 > 0.f ? v1 : 0.f;
            ++tot;
            mw &= mw - 1;
        }
    }
    nbr16[(size_t)i * CAP + lane] = myent;         // coalesced 128B, sentinel-padded
    if (lane == 0) deg[i] = tot > CAP ? CAP : tot;
    ((float2*)fv1)[(size_t)i * 64 + lane] = acc;   // coalesced 512B
}

// ---------- kernel 3: wave-per-node fv_2 (ballot count restored) ----------
// fv2[i] = sum_{j in M2(i)} |M2(i) ∩ N(j)| * fv1[j]. Per-wave LDS slices only;
// same-wave LDS is in-order (no __syncthreads anywhere).
__global__ void fv2_kernel(const uint64_t* __restrict__ A,
                           const u16* __restrict__ nbr16, const int* __restrict__ deg,
                           const float* __restrict__ fv1, float* __restrict__ out) {
    __shared__ uint64_t m2rows[4][64];   // 512B per wave
    __shared__ u16 list2s[4][MAXJ];      // 1KB per wave
    int tid = threadIdx.x, lane = tid & 63, wave = tid >> 6;
    int i = blockIdx.x * 4 + wave;
    if (i >= M_NODES) return;

    int n1 = deg[i];
    int nbr_l = (int)nbr16[(size_t)i * CAP + lane];   // list1 in register

    // M2 row: OR of neighbors' A rows (coalesced 504B each), unroll-2.
    uint64_t o = 0;
    {
        int l = 0;
        for (; l + 1 < n1; l += 2) {
            int j0 = __shfl(nbr_l, l, 64);
            int j1 = __shfl(nbr_l, l + 1, 64);
            if (lane < NW) o |= A[(size_t)j0 * NW + lane] | A[(size_t)j1 * NW + lane];
        }
        if (l < n1) {
            int j0 = __shfl(nbr_l, l, 64);
            if (lane < NW) o |= A[(size_t)j0 * NW + lane];
        }
    }
    uint64_t* m2row = m2rows[wave];
    u16* list2 = list2s[wave];
    m2row[lane] = o;                     // lane 63 writes 0 -> sentinel-safe

    // scan + deterministic ascending enumerate of M2(i), by this wave.
    int c = __popcll(o);
    int incl = wave64_incl_scan(c, lane);
    int oo = incl - c;
    int base = lane * 64;
    uint64_t mm = o;
    while (mm) {
        int b = __builtin_ctzll(mm);
        if (oo < MAXJ) list2[oo] = (u16)(base + b);
        ++oo;
        mm &= mm - 1;
    }
    int n2 = __shfl(incl, 63, 64);
    if (n2 > MAXJ) n2 = MAXJ;
    __builtin_amdgcn_wave_barrier();     // keep LDS writes ordered before reads

    // fused counts + weighted sum: this wave does ALL j, ascending, unroll-4
    // (8 independent global loads in flight per round).
    const float2* fv1v = (const float2*)fv1;     // row = 64 float2
    float2 acc = {0.f, 0.f};
    int l = 0;
    for (; l + 3 < n2; l += 4) {
        int j0 = list2[l], j1 = list2[l + 1], j2 = list2[l + 2], j3 = list2[l + 3];
        int u0 = nbr16[(size_t)j0 * CAP + lane];     // 128B coalesced
        int u1 = nbr16[(size_t)j1 * CAP + lane];
        int u2 = nbr16[(size_t)j2 * CAP + lane];
        int u3 = nbr16[(size_t)j3 * CAP + lane];
        float2 r0 = fv1v[(size_t)j0 * 64 + lane];    // 512B coalesced
        float2 r1 = fv1v[(size_t)j1 * 64 + lane];
        float2 r2 = fv1v[(size_t)j2 * 64 + lane];
        float2 r3 = fv1v[(size_t)j3 * 64 + lane];
        bool p0 = (m2row[u0 >> 6] >> (u0 & 63)) & 1ull;
        bool p1 = (m2row[u1 >> 6] >> (u1 & 63)) & 1ull;
        bool p2 = (m2row[u2 >> 6] >> (u2 & 63)) & 1ull;
        bool p3 = (m2row[u3 >> 6] >> (u3 & 63)) & 1ull;
        float c0 = (float)__popcll(__ballot(p0));    // exact small ints
        float c1 = (float)__popcll(__ballot(p1));
        float c2 = (float)__popcll(__ballot(p2));
        float c3 = (float)__popcll(__ballot(p3));
        acc.x = fmaf(c0, r0.x, acc.x); acc.y = fmaf(c0, r0.y, acc.y);
        acc.x = fmaf(c1, r1.x, acc.x); acc.y = fmaf(c1, r1.y, acc.y);
        acc.x = fmaf(c2, r2.x, acc.x); acc.y = fmaf(c2, r2.y, acc.y);
        acc.x = fmaf(c3, r3.x, acc.x); acc.y = fmaf(c3, r3.y, acc.y);
    }
    for (; l < n2; ++l) {
        int j0 = list2[l];
        int u0 = nbr16[(size_t)j0 * CAP + lane];
        float2 r0 = fv1v[(size_t)j0 * 64 + lane];
        bool p0 = (m2row[u0 >> 6] >> (u0 & 63)) & 1ull;
        float c0 = (float)__popcll(__ballot(p0));
        acc.x = fmaf(c0, r0.x, acc.x); acc.y = fmaf(c0, r0.y, acc.y);
    }
    ((float2*)out)[(size_t)i * 64 + lane] = acc;     // coalesced 512B
}

extern "C" void kernel_launch(void* const* d_in, const int* in_sizes, int n_in,
                              void* d_out, int out_size, void* d_ws, size_t ws_size,
                              hipStream_t stream) {
    const float* node_loc = (const float*)d_in[0];  // [4000,2]
    const float* td       = (const float*)d_in[1];  // [4000,1]
    const float* depot    = (const float*)d_in[2];  // [1,2]
    const float* W0w      = (const float*)d_in[3];  // [128,3]
    const float* W0b      = (const float*)d_in[4];  // [128]
    float* out = (float*)d_out;                     // [4001,128]

    char* base = (char*)d_ws;
    size_t off = 0;
    auto carve = [&](size_t bytes) {
        char* p = base + off;
        off = (off + bytes + 511) & ~(size_t)511;
        return p;
    };
    uint64_t* A     = (uint64_t*)carve((size_t)M_NODES * NW * sizeof(uint64_t));  // ~2.0 MB
    float*    fv1   = (float*)   carve((size_t)M_NODES * 128 * sizeof(float));    // ~2.0 MB
    u16*      nbr16 = (u16*)     carve((size_t)M_NODES * CAP * sizeof(u16));      // ~0.5 MB
    int*      deg   = (int*)     carve((size_t)M_NODES * sizeof(int));            // 16 KB

    prep_kernel<<<ADJ_BLOCKS, 256, 0, stream>>>(node_loc, depot, A);
    fv1csr_kernel<<<NODE_BLOCKS, 256, 0, stream>>>(A, node_loc, td, depot, W0w, W0b,
                                                   nbr16, deg, fv1);
    fv2_kernel<<<NODE_BLOCKS, 256, 0, stream>>>(A, nbr16, deg, fv1, out);
}